// Round 6
// baseline (80.870 us; speedup 1.0000x reference)
//
#include <hip/hip_runtime.h>
#include <math.h>

#define EPS 1e-9f

// Block = 256 threads (4 waves) owns 128 bodies: lane l -> bodies i0 = bx*128+l
// and i1 = i0+64 (both same type; Nc=4096 is 128-aligned). blockIdx.y picks a
// 256-partner super-chunk, staged cooperatively into LDS; wave w consumes its
// own 64-partner window (broadcast ds_read_b128, 2 pair-computations per read).
// 4 waves LDS-reduce -> 2 atomics per body per block. out zeroed beforehand;
// blockIdx.y==0 blocks fold the base position in.
__global__ __launch_bounds__(256)
void collide(const float2* __restrict__ cpos,
             const float*  __restrict__ crad,
             const float2* __restrict__ apos,
             const float2* __restrict__ ahalf,
             float* __restrict__ out,
             int Nc, int Na) {
    const int lane = threadIdx.x & 63;
    const int w    = threadIdx.x >> 6;
    const int i0   = blockIdx.x * 128 + lane;
    const int i1   = i0 + 64;

    __shared__ float4 sP[256];
    {
        const int p = blockIdx.y * 256 + (int)threadIdx.x;   // always < Ntot (24*256=6144)
        float4 v;
        if (p < Nc) {
            const float2 c = cpos[p];
            v = make_float4(c.x, c.y, crad[p], 0.0f);
        } else {
            const float2 a = apos[p - Nc];
            const float2 h = ahalf[p - Nc];
            v = make_float4(a.x, a.y, h.x, h.y);
        }
        sP[threadIdx.x] = v;
    }
    __syncthreads();

    const int off   = w << 6;                      // wave's window in sP
    const int jbase = blockIdx.y * 256 + off;      // global partner base (uniform)
    const bool bodyC = (blockIdx.x * 128) < Nc;    // uniform branch
    const bool partC = (jbase < Nc);               // uniform branch

    float a0x = 0.f, a0y = 0.f, a1x = 0.f, a1y = 0.f;

    if (bodyC) {
        const float2 p0 = cpos[i0]; const float r0 = crad[i0];
        const float2 p1 = cpos[i1]; const float r1 = crad[i1];
        if (partC) {
            #pragma unroll 8
            for (int k = 0; k < 64; ++k) {
                const float4 q = sP[off + k];
                {   // body 0: circle-circle (self excluded by d2>EPS)
                    const float dx = p0.x - q.x, dy = p0.y - q.y;
                    const float d2 = fmaf(dx, dx, dy * dy);
                    const float r  = __builtin_amdgcn_rsqf(d2);
                    const float pen = (r0 + q.z) - d2 * r;
                    const float s = (d2 > EPS && pen > 0.f) ? 0.5f * pen * r : 0.f;
                    a0x = fmaf(s, dx, a0x); a0y = fmaf(s, dy, a0y);
                }
                {   // body 1
                    const float dx = p1.x - q.x, dy = p1.y - q.y;
                    const float d2 = fmaf(dx, dx, dy * dy);
                    const float r  = __builtin_amdgcn_rsqf(d2);
                    const float pen = (r1 + q.z) - d2 * r;
                    const float s = (d2 > EPS && pen > 0.f) ? 0.5f * pen * r : 0.f;
                    a1x = fmaf(s, dx, a1x); a1y = fmaf(s, dy, a1y);
                }
            }
        } else {
            #pragma unroll 8
            for (int k = 0; k < 64; ++k) {
                const float4 q = sP[off + k];
                {   // body 0: circle vs box (push on circle)
                    const float rx = p0.x - q.x, ry = p0.y - q.y;
                    const float cx = fminf(fmaxf(rx, -q.z), q.z);
                    const float cy = fminf(fmaxf(ry, -q.w), q.w);
                    const float dx = rx - cx, dy = ry - cy;
                    const float d2 = fmaf(dx, dx, dy * dy);
                    const float r  = __builtin_amdgcn_rsqf(d2);
                    const float pen = r0 - d2 * r;
                    const float s = (d2 > EPS && pen > 0.f) ? 0.5f * pen * r : 0.f;
                    a0x = fmaf(s, dx, a0x); a0y = fmaf(s, dy, a0y);
                }
                {   // body 1
                    const float rx = p1.x - q.x, ry = p1.y - q.y;
                    const float cx = fminf(fmaxf(rx, -q.z), q.z);
                    const float cy = fminf(fmaxf(ry, -q.w), q.w);
                    const float dx = rx - cx, dy = ry - cy;
                    const float d2 = fmaf(dx, dx, dy * dy);
                    const float r  = __builtin_amdgcn_rsqf(d2);
                    const float pen = r1 - d2 * r;
                    const float s = (d2 > EPS && pen > 0.f) ? 0.5f * pen * r : 0.f;
                    a1x = fmaf(s, dx, a1x); a1y = fmaf(s, dy, a1y);
                }
            }
        }
    } else {
        const float2 b0 = apos[i0 - Nc]; const float2 h0 = ahalf[i0 - Nc];
        const float2 b1 = apos[i1 - Nc]; const float2 h1 = ahalf[i1 - Nc];
        if (partC) {
            #pragma unroll 8
            for (int k = 0; k < 64; ++k) {
                const float4 q = sP[off + k];
                {   // body 0: circle partner, equal-and-opposite on box
                    const float rx = q.x - b0.x, ry = q.y - b0.y;
                    const float cx = fminf(fmaxf(rx, -h0.x), h0.x);
                    const float cy = fminf(fmaxf(ry, -h0.y), h0.y);
                    const float dx = rx - cx, dy = ry - cy;
                    const float d2 = fmaf(dx, dx, dy * dy);
                    const float r  = __builtin_amdgcn_rsqf(d2);
                    const float pen = q.z - d2 * r;
                    const float s = (d2 > EPS && pen > 0.f) ? -0.5f * pen * r : 0.f;
                    a0x = fmaf(s, dx, a0x); a0y = fmaf(s, dy, a0y);
                }
                {   // body 1
                    const float rx = q.x - b1.x, ry = q.y - b1.y;
                    const float cx = fminf(fmaxf(rx, -h1.x), h1.x);
                    const float cy = fminf(fmaxf(ry, -h1.y), h1.y);
                    const float dx = rx - cx, dy = ry - cy;
                    const float d2 = fmaf(dx, dx, dy * dy);
                    const float r  = __builtin_amdgcn_rsqf(d2);
                    const float pen = q.z - d2 * r;
                    const float s = (d2 > EPS && pen > 0.f) ? -0.5f * pen * r : 0.f;
                    a1x = fmaf(s, dx, a1x); a1y = fmaf(s, dy, a1y);
                }
            }
        } else {
            #pragma unroll 8
            for (int k = 0; k < 64; ++k) {
                const int j = jbase + k;                   // uniform
                const float4 q = sP[off + k];
                {   // body 0: box-box minimum-overlap axis (exclude self)
                    const float dax = b0.x - q.x, day = b0.y - q.y;
                    const float ovx = h0.x + q.z - fabsf(dax);
                    const float ovy = h0.y + q.w - fabsf(day);
                    const bool hit = (j != i0) && (ovx > 0.f) && (ovy > 0.f);
                    const bool ux  = ovx <= ovy;
                    a0x += (hit && ux)  ? 0.5f * ovx * (dax >= 0.f ? 1.f : -1.f) : 0.f;
                    a0y += (hit && !ux) ? 0.5f * ovy * (day >= 0.f ? 1.f : -1.f) : 0.f;
                }
                {   // body 1
                    const float dax = b1.x - q.x, day = b1.y - q.y;
                    const float ovx = h1.x + q.z - fabsf(dax);
                    const float ovy = h1.y + q.w - fabsf(day);
                    const bool hit = (j != i1) && (ovx > 0.f) && (ovy > 0.f);
                    const bool ux  = ovx <= ovy;
                    a1x += (hit && ux)  ? 0.5f * ovx * (dax >= 0.f ? 1.f : -1.f) : 0.f;
                    a1y += (hit && !ux) ? 0.5f * ovy * (day >= 0.f ? 1.f : -1.f) : 0.f;
                }
            }
        }
    }

    // block reduction: 4 waves -> 1 partial per body -> atomics
    __shared__ float2 red[4][128];
    red[w][lane]      = make_float2(a0x, a0y);
    red[w][lane + 64] = make_float2(a1x, a1y);
    __syncthreads();
    const int t = threadIdx.x;
    if (t < 128) {
        const float2 s0 = red[0][t], s1 = red[1][t], s2 = red[2][t], s3 = red[3][t];
        float sx = s0.x + s1.x + s2.x + s3.x;
        float sy = s0.y + s1.y + s2.y + s3.y;
        const int i = blockIdx.x * 128 + t;
        if (blockIdx.y == 0) {
            const float2 base = (i < Nc) ? cpos[i] : apos[i - Nc];
            sx += base.x; sy += base.y;
        }
        atomicAdd(&out[2 * i],     sx);
        atomicAdd(&out[2 * i + 1], sy);
    }
}

extern "C" void kernel_launch(void* const* d_in, const int* in_sizes, int n_in,
                              void* d_out, int out_size, void* d_ws, size_t ws_size,
                              hipStream_t stream) {
    (void)n_in; (void)d_ws; (void)ws_size;

    const float2* cpos  = (const float2*)d_in[0];
    const float*  crad  = (const float*) d_in[1];
    const float2* apos  = (const float2*)d_in[2];
    const float2* ahalf = (const float2*)d_in[3];

    const int Nc   = in_sizes[1];       // 4096
    const int Na   = in_sizes[2] / 2;   // 2048
    const int Ntot = Nc + Na;           // 6144

    hipMemsetAsync(d_out, 0, (size_t)out_size * sizeof(float), stream);

    const int gx = (Ntot + 127) / 128;    // 48 body tiles (128 bodies, 2/lane)
    const int gy = (Ntot + 255) / 256;    // 24 partner super-chunks
    dim3 grid(gx, gy, 1);
    collide<<<grid, 256, 0, stream>>>(cpos, crad, apos, ahalf, (float*)d_out, Nc, Na);
}

// Round 7
// 79.400 us; speedup vs baseline: 1.0185x; 1.0185x over previous
//
#include <hip/hip_runtime.h>
#include <math.h>

#define EPS 1e-9f

// P[i]: circle i<Nc -> (x, y, radius, 0); box -> (x, y, half.x, half.y).
// Also seeds out with base positions (collide only atomically adds corrections).
__global__ void prep(const float2* __restrict__ cpos,
                     const float*  __restrict__ crad,
                     const float2* __restrict__ apos,
                     const float2* __restrict__ ahalf,
                     float4* __restrict__ P,
                     float2* __restrict__ out,
                     int Nc, int Ntot) {
    int i = blockIdx.x * blockDim.x + threadIdx.x;
    if (i >= Ntot) return;
    if (i < Nc) {
        const float2 p = cpos[i];
        P[i]   = make_float4(p.x, p.y, crad[i], 0.0f);
        out[i] = p;
    } else {
        const float2 a = apos[i - Nc];
        const float2 h = ahalf[i - Nc];
        P[i]   = make_float4(a.x, a.y, h.x, h.y);
        out[i] = a;
    }
}

// Lane-per-body, wave-per-(64-body group x 64-partner chunk). Partner index is
// wave-uniform -> scalar loads; kernel is VALU-issue-bound, so pair math is
// instruction-minimized:
//  - pen via fmaf(-d2, r, R); (pen>0) via fmaxf(t,0)  [NaN-safe: fmax(NaN,0)=0]
//  - d2>EPS guard only where it can trigger: diagonal CC tiles (self-pair) and
//    circle-box (center-inside-box => d2==0 is common)
//  - box-box sign via copysignf; j!=i only on diagonal tiles (uniform branch)
__global__ __launch_bounds__(256)
void collide(const float4* __restrict__ P,
             float* __restrict__ out,
             int Nc, int Ntot) {
    const int lane  = threadIdx.x & 63;
    const int w     = __builtin_amdgcn_readfirstlane(threadIdx.x >> 6);
    const int ibase = (int)(blockIdx.x << 6);
    const int i     = ibase + lane;
    const int jbase = (blockIdx.y * 4 + w) << 6;       // uniform

    const float4 me = P[i];
    float ax = 0.0f, ay = 0.0f;

    const bool bodyC = ibase < Nc;                     // uniform
    const bool partC = jbase < Nc;                     // uniform
    const bool diag  = (jbase == ibase);               // uniform

    if (bodyC) {
        const float px = me.x, py = me.y, ri = me.z;
        if (partC) {
            if (diag) {
                #pragma unroll 8
                for (int k = 0; k < 64; ++k) {
                    const float4 q = P[jbase + k];
                    const float dx = px - q.x, dy = py - q.y;
                    const float d2 = fmaf(dx, dx, dy * dy);
                    const float r  = __builtin_amdgcn_rsqf(d2);
                    const float t  = fmaf(-d2, r, ri + q.z);        // pen
                    float s = fmaxf(0.5f * t * r, 0.0f);
                    s = (d2 > EPS) ? s : 0.0f;                      // self-pair guard
                    ax = fmaf(s, dx, ax); ay = fmaf(s, dy, ay);
                }
            } else {
                #pragma unroll 8
                for (int k = 0; k < 64; ++k) {
                    const float4 q = P[jbase + k];
                    const float dx = px - q.x, dy = py - q.y;
                    const float d2 = fmaf(dx, dx, dy * dy);
                    const float r  = __builtin_amdgcn_rsqf(d2);
                    const float t  = fmaf(-d2, r, ri + q.z);
                    const float s  = fmaxf(0.5f * t * r, 0.0f);     // no guard: distinct circles
                    ax = fmaf(s, dx, ax); ay = fmaf(s, dy, ay);
                }
            }
        } else {
            #pragma unroll 8
            for (int k = 0; k < 64; ++k) {
                const float4 q = P[jbase + k];
                const float rx = px - q.x, ry = py - q.y;
                const float cx = fminf(fmaxf(rx, -q.z), q.z);       // v_med3
                const float cy = fminf(fmaxf(ry, -q.w), q.w);
                const float dx = rx - cx, dy = ry - cy;
                const float d2 = fmaf(dx, dx, dy * dy);
                const float r  = __builtin_amdgcn_rsqf(d2);
                const float t  = fmaf(-d2, r, ri);
                float s = fmaxf(0.5f * t * r, 0.0f);
                s = (d2 > EPS) ? s : 0.0f;                          // center-inside-box guard
                ax = fmaf(s, dx, ax); ay = fmaf(s, dy, ay);
            }
        }
    } else {
        const float bx = me.x, by = me.y, hx = me.z, hy = me.w;
        if (partC) {
            #pragma unroll 8
            for (int k = 0; k < 64; ++k) {
                const float4 q = P[jbase + k];
                const float rx = q.x - bx, ry = q.y - by;
                const float cx = fminf(fmaxf(rx, -hx), hx);
                const float cy = fminf(fmaxf(ry, -hy), hy);
                const float dx = rx - cx, dy = ry - cy;
                const float d2 = fmaf(dx, dx, dy * dy);
                const float r  = __builtin_amdgcn_rsqf(d2);
                const float t  = fmaf(-d2, r, q.z);
                float s = fmaxf(0.5f * t * r, 0.0f);
                s = (d2 > EPS) ? s : 0.0f;
                ax = fmaf(-s, dx, ax); ay = fmaf(-s, dy, ay);       // opposite on box
            }
        } else {
            if (diag) {
                #pragma unroll 8
                for (int k = 0; k < 64; ++k) {
                    const int j = jbase + k;
                    const float4 q = P[j];
                    const float dax = bx - q.x, day = by - q.y;
                    const float ovx = (hx + q.z) - fabsf(dax);
                    const float ovy = (hy + q.w) - fabsf(day);
                    const bool hit = (fminf(ovx, ovy) > 0.0f) && (j != i);
                    const bool ux  = ovx <= ovy;
                    const float pxv = copysignf(0.5f * ovx, dax);
                    const float pyv = copysignf(0.5f * ovy, day);
                    ax += (hit && ux)  ? pxv : 0.0f;
                    ay += (hit && !ux) ? pyv : 0.0f;
                }
            } else {
                #pragma unroll 8
                for (int k = 0; k < 64; ++k) {
                    const float4 q = P[jbase + k];
                    const float dax = bx - q.x, day = by - q.y;
                    const float ovx = (hx + q.z) - fabsf(dax);
                    const float ovy = (hy + q.w) - fabsf(day);
                    const bool hit = fminf(ovx, ovy) > 0.0f;
                    const bool ux  = ovx <= ovy;
                    const float pxv = copysignf(0.5f * ovx, dax);
                    const float pyv = copysignf(0.5f * ovy, day);
                    ax += (hit && ux)  ? pxv : 0.0f;
                    ay += (hit && !ux) ? pyv : 0.0f;
                }
            }
        }
    }

    // block reduction: 4 waves -> 1 partial per body -> 2 atomics
    __shared__ float sax[4][64];
    __shared__ float say[4][64];
    sax[w][lane] = ax;
    say[w][lane] = ay;
    __syncthreads();
    if (w == 0) {
        const float tx = sax[0][lane] + sax[1][lane] + sax[2][lane] + sax[3][lane];
        const float ty = say[0][lane] + say[1][lane] + say[2][lane] + say[3][lane];
        atomicAdd(&out[2 * i],     tx);
        atomicAdd(&out[2 * i + 1], ty);
    }
}

extern "C" void kernel_launch(void* const* d_in, const int* in_sizes, int n_in,
                              void* d_out, int out_size, void* d_ws, size_t ws_size,
                              hipStream_t stream) {
    (void)n_in; (void)out_size; (void)ws_size;

    const float2* cpos  = (const float2*)d_in[0];
    const float*  crad  = (const float*) d_in[1];
    const float2* apos  = (const float2*)d_in[2];
    const float2* ahalf = (const float2*)d_in[3];

    const int Nc   = in_sizes[1];       // 4096
    const int Na   = in_sizes[2] / 2;   // 2048
    const int Ntot = Nc + Na;           // 6144 (96 * 64)

    float4* P = (float4*)d_ws;

    prep<<<(Ntot + 255) / 256, 256, 0, stream>>>(cpos, crad, apos, ahalf,
                                                 P, (float2*)d_out, Nc, Ntot);

    const int gx = (Ntot + 63) / 64;      // 96 body groups
    const int gy = (Ntot + 255) / 256;    // 24 partner super-chunks (x4 waves)
    dim3 grid(gx, gy, 1);
    collide<<<grid, 256, 0, stream>>>(P, (float*)d_out, Nc, Ntot);
}